// Round 5
// baseline (499.652 us; speedup 1.0000x reference)
//
#include <hip/hip_runtime.h>
#include <math.h>

namespace {
constexpr int IH = 224, IW = 224;
constexpr int H2 = 67, W2 = 67;
constexpr int MH = 56, MW = 56;
constexpr int CI = 3, CM = 21;
constexpr int ND = 6;
constexpr int K = 48;
constexpr int HW = IH * IW;    // 50176
constexpr int HW2 = H2 * W2;   // 4489
constexpr float EPS = 1e-8f;
__device__ __constant__ int DILS_C[ND] = {1, 2, 4, 8, 12, 24};
}

struct PosArr { float v[K]; };

__device__ __forceinline__ float wsum64(float v) {
    #pragma unroll
    for (int off = 1; off < 64; off <<= 1) v += __shfl_xor(v, off);
    return v;
}

// ---------------- bilinear downsample imgs 224->67 (align_corners) ----------
__global__ void k_img_down(const float* __restrict__ img, float* __restrict__ img2) {
    int t = blockIdx.x * blockDim.x + threadIdx.x;
    if (t >= CI * HW2) return;
    int c = t / HW2, r = t % HW2;
    int y = r / W2, x = r % W2;
    float fy = (float)y * ((float)(IH - 1) / (float)(H2 - 1));
    float fx = (float)x * ((float)(IW - 1) / (float)(W2 - 1));
    int y0 = (int)floorf(fy); int y1 = min(y0 + 1, IH - 1); float wy = fy - (float)y0;
    int x0 = (int)floorf(fx); int x1 = min(x0 + 1, IW - 1); float wx = fx - (float)x0;
    const float* p = img + c * HW;
    float v00 = p[y0 * IW + x0], v01 = p[y0 * IW + x1];
    float v10 = p[y1 * IW + x0], v11 = p[y1 * IW + x1];
    float r0 = v00 * (1.f - wy) + v10 * wy;
    float r1 = v01 * (1.f - wy) + v11 * wy;
    img2[t] = r0 * (1.f - wx) + r1 * wx;
}

// ---------------- low-res affinity: one WAVE per pixel ----------------------
// aff2 layout [HW2][K]; stores sum over channels of (|n-center|/std)^2
__global__ void k_aff2(const float* __restrict__ img2, float* __restrict__ aff2) {
    int gtid = blockIdx.x * blockDim.x + threadIdx.x;
    int wave = gtid >> 6;
    int lane = threadIdx.x & 63;
    if (wave >= HW2) return;
    int t = wave;
    int y = t / W2, x = t % W2;

    int k = (lane < K) ? lane : (K - 1);
    int di = k >> 3, o = k & 7;
    int d = DILS_C[di];
    int ym = max(y - d, 0), yp = min(y + d, H2 - 1);
    int xm = max(x - d, 0), xp = min(x + d, W2 - 1);
    int ki = (0x22211000u >> (o * 4)) & 3;
    int kj = (0x21020210u >> (o * 4)) & 3;
    int ry = ki == 0 ? ym : (ki == 1 ? y : yp);
    int rx = kj == 0 ? xm : (kj == 1 ? x : xp);
    int nidx = ry * W2 + rx;

    float av = 0.f;
    #pragma unroll
    for (int c = 0; c < CI; ++c) {
        const float* p = img2 + c * HW2;
        float center = p[y * W2 + x];
        float v = p[nidx];
        float vv = (lane < K) ? v : 0.f;
        float s = wsum64(vv);
        float s2 = wsum64(vv * vv);
        float mean = s * (1.f / (float)K);
        float ss = s2 - (float)K * mean * mean;
        float stdv = sqrtf(fmaxf(ss, 0.f) * (1.f / (float)(K - 1)));
        float inv = 1.f / (stdv + EPS);
        float tt = fabsf(v - center) * inv;
        av += tt * tt;
    }
    if (lane < K) aff2[(size_t)t * K + k] = av;
}

// ---------------- full-res aff + upsampled aff2 + pos -> aff_total ----------
// 16 lanes per pixel (4 px/wave); lane handles k = lane, lane+16, lane+32.
// aff2 layout [HW2][K]; writes afft[t*K + k]
__global__ void k_aff_total(const float* __restrict__ img,
                            const float* __restrict__ aff2,
                            float* __restrict__ afft, PosArr pos) {
    int gid = blockIdx.x * blockDim.x + threadIdx.x;
    int t = gid >> 4;
    int lane = threadIdx.x & 15;
    if (t >= HW) return;
    int y = t / IW, x = t % IW;

    int nidx[3];
    int kk[3];
    #pragma unroll
    for (int s = 0; s < 3; ++s) {
        int k = lane + 16 * s;
        kk[s] = k;
        int di = k >> 3, o = k & 7;
        int d = DILS_C[di];
        int ki = (0x22211000u >> (o * 4)) & 3;
        int kj = (0x21020210u >> (o * 4)) & 3;
        int ym = max(y - d, 0), yp = min(y + d, IH - 1);
        int xm = max(x - d, 0), xp = min(x + d, IW - 1);
        int ry = ki == 0 ? ym : (ki == 1 ? y : yp);
        int rx = kj == 0 ? xm : (kj == 1 ? x : xp);
        nidx[s] = ry * IW + rx;
    }

    // full-res affinity accumulated over channels
    float av0 = 0.f, av1 = 0.f, av2 = 0.f;
    #pragma unroll
    for (int c = 0; c < CI; ++c) {
        const float* p = img + c * HW;
        float center = p[y * IW + x];
        float n0 = p[nidx[0]], n1 = p[nidx[1]], n2 = p[nidx[2]];
        float s1 = n0 + n1 + n2;
        float s2 = n0 * n0 + n1 * n1 + n2 * n2;
        #pragma unroll
        for (int off = 1; off < 16; off <<= 1) {
            s1 += __shfl_xor(s1, off, 16);
            s2 += __shfl_xor(s2, off, 16);
        }
        float mean = s1 * (1.f / (float)K);
        float ss = s2 - (float)K * mean * mean;
        float inv = 1.f / (sqrtf(fmaxf(ss, 0.f) * (1.f / (float)(K - 1))) + EPS);
        float t0 = fabsf(n0 - center) * inv; av0 += t0 * t0;
        float t1 = fabsf(n1 - center) * inv; av1 += t1 * t1;
        float t2 = fabsf(n2 - center) * inv; av2 += t2 * t2;
    }
    const float sc = -(1.f / (float)CI) / (0.3f * 0.3f);
    av0 *= sc; av1 *= sc; av2 *= sc;
    float m1 = fmaxf(av0, fmaxf(av1, av2));
    #pragma unroll
    for (int off = 1; off < 16; off <<= 1) m1 = fmaxf(m1, __shfl_xor(m1, off, 16));
    float e0 = expf(av0 - m1), e1 = expf(av1 - m1), e2 = expf(av2 - m1);
    float es = e0 + e1 + e2;
    #pragma unroll
    for (int off = 1; off < 16; off <<= 1) es += __shfl_xor(es, off, 16);
    float r1 = 1.f / es;

    // bilinear sample of aff2 (67->224, align_corners), then softmax
    float fy = (float)y * ((float)(H2 - 1) / (float)(IH - 1));
    float fx = (float)x * ((float)(W2 - 1) / (float)(IW - 1));
    int y0 = (int)floorf(fy); int y1 = min(y0 + 1, H2 - 1); float wy = fy - (float)y0;
    int x0 = (int)floorf(fx); int x1 = min(x0 + 1, W2 - 1); float wx = fx - (float)x0;
    const float* q00 = aff2 + (size_t)(y0 * W2 + x0) * K;
    const float* q01 = aff2 + (size_t)(y0 * W2 + x1) * K;
    const float* q10 = aff2 + (size_t)(y1 * W2 + x0) * K;
    const float* q11 = aff2 + (size_t)(y1 * W2 + x1) * K;
    float w00 = (1.f - wy) * (1.f - wx), w01 = (1.f - wy) * wx;
    float w10 = wy * (1.f - wx), w11 = wy * wx;
    const float sc2 = -(1.f / (float)CI);
    float b0 = (q00[kk[0]] * w00 + q01[kk[0]] * w01 + q10[kk[0]] * w10 + q11[kk[0]] * w11) * sc2;
    float b1 = (q00[kk[1]] * w00 + q01[kk[1]] * w01 + q10[kk[1]] * w10 + q11[kk[1]] * w11) * sc2;
    float b2 = (q00[kk[2]] * w00 + q01[kk[2]] * w01 + q10[kk[2]] * w10 + q11[kk[2]] * w11) * sc2;
    float m2 = fmaxf(b0, fmaxf(b1, b2));
    #pragma unroll
    for (int off = 1; off < 16; off <<= 1) m2 = fmaxf(m2, __shfl_xor(m2, off, 16));
    float f0 = expf(b0 - m2), f1 = expf(b1 - m2), f2 = expf(b2 - m2);
    float fs = f0 + f1 + f2;
    #pragma unroll
    for (int off = 1; off < 16; off <<= 1) fs += __shfl_xor(fs, off, 16);
    float r2 = 1.f / fs;

    float* o = afft + (size_t)t * K;
    o[kk[0]] = e0 * r1 + f0 * r2 + pos.v[kk[0]];
    o[kk[1]] = e1 * r1 + f1 * r2 + pos.v[kk[1]];
    o[kk[2]] = e2 * r1 + f2 * r2 + pos.v[kk[2]];
}

// ---------------- mask upsample 56 -> 224 -----------------------------------
__global__ void k_mask_up(const float* __restrict__ m, float* __restrict__ mu) {
    int t = blockIdx.x * blockDim.x + threadIdx.x;
    if (t >= CM * HW) return;
    int c = t / HW, r = t % HW;
    int y = r / IW, x = r % IW;
    float fy = (float)y * ((float)(MH - 1) / (float)(IH - 1));
    float fx = (float)x * ((float)(MW - 1) / (float)(IW - 1));
    int y0 = (int)floorf(fy); int y1 = min(y0 + 1, MH - 1); float wy = fy - (float)y0;
    int x0 = (int)floorf(fx); int x1 = min(x0 + 1, MW - 1); float wx = fx - (float)x0;
    const float* p = m + c * MH * MW;
    float v00 = p[y0 * MW + x0], v01 = p[y0 * MW + x1];
    float v10 = p[y1 * MW + x0], v11 = p[y1 * MW + x1];
    float r0 = v00 * (1.f - wy) + v10 * wy;
    float r1 = v01 * (1.f - wy) + v11 * wy;
    mu[t] = r0 * (1.f - wx) + r1 * wx;
}

// ---------------- one propagation iteration ---------------------------------
// Block = 7 waves x 7 channels x 112-px row tile. Each wave stages its
// channel's 13 halo rows (x-clamp BAKED into LDS) then each lane computes
// 2 adjacent pixels with float2 LDS reads. 3 channel-groups cover CM=21.
__global__ __launch_bounds__(448, 2) void k_prop(const float* __restrict__ min_,
                                                 const float* __restrict__ afft,
                                                 float* __restrict__ mout) {
    __shared__ float lds[7 * 13 * 160];   // 58.2 KB
    int w = threadIdx.x >> 6;
    int lane = threadIdx.x & 63;
    // bijective XCD swizzle over 1344 blocks = 8 * 168; id = tp*3+cg keeps
    // all 3 channel-groups of the same rows on one XCD (afft/mask locality)
    int bid = blockIdx.x;
    int sw = (bid & 7) * 168 + (bid >> 3);
    int tp = sw / 3;              // 0..447 tile position
    int cg = sw - tp * 3;         // 0..2 channel group
    int y0 = tp >> 1;
    int x0 = (tp & 1) * 112;
    int c = cg * 7 + w;

    // ---- stage 13 rows x 160 px of channel c
    const int ROW_DY[13] = {-24, -12, -8, -4, -2, -1, 0, 1, 2, 4, 8, 12, 24};
    const float* mc = min_ + (size_t)c * HW;
    float* L = lds + w * 2080;
    #pragma unroll
    for (int r = 0; r < 13; ++r) {
        int gy = min(max(y0 + ROW_DY[r], 0), IH - 1);
        const float* row = mc + gy * IW;
        #pragma unroll
        for (int b = 0; b < 3; ++b) {
            int ix = b * 64 + lane;
            if (ix < 160) {
                int gx = min(max(x0 - 24 + ix, 0), IW - 1);
                L[r * 160 + ix] = row[gx];
            }
        }
    }
    __syncthreads();

    if (lane >= 56) return;
    int j0 = 2 * lane;
    int t = y0 * IW + x0 + j0;
    const float* A0 = afft + (size_t)t * K;
    const float* A1 = A0 + K;
    const float* Lb = L + (j0 + 24);

    const int RMI[6] = {5, 4, 3, 2, 1, 0};
    const int RPI[6] = {7, 8, 9, 10, 11, 12};
    const int DILS[6] = {1, 2, 4, 8, 12, 24};
    float acc0 = 0.f, acc1 = 0.f;
    #pragma unroll
    for (int di = 0; di < 6; ++di) {
        const int d = DILS[di];
        const float* Lm = Lb + RMI[di] * 160;
        const float* Lc = Lb + 6 * 160;
        const float* Lp = Lb + RPI[di] * 160;
        float4 a0a = *(const float4*)(A0 + di * 8);
        float4 a0b = *(const float4*)(A0 + di * 8 + 4);
        float4 a1a = *(const float4*)(A1 + di * 8);
        float4 a1b = *(const float4*)(A1 + di * 8 + 4);
        float2 m;
        // dx = +/-d loads: aligned float2 iff d even; dx=0 loads always aligned
        if (d & 1) {
            m = make_float2(Lm[-d], Lm[-d + 1]); acc0 += m.x * a0a.x; acc1 += m.y * a1a.x;
            m = *(const float2*)(Lm);            acc0 += m.x * a0a.y; acc1 += m.y * a1a.y;
            m = make_float2(Lm[d], Lm[d + 1]);   acc0 += m.x * a0a.z; acc1 += m.y * a1a.z;
            m = make_float2(Lc[-d], Lc[-d + 1]); acc0 += m.x * a0a.w; acc1 += m.y * a1a.w;
            m = make_float2(Lc[d], Lc[d + 1]);   acc0 += m.x * a0b.x; acc1 += m.y * a1b.x;
            m = make_float2(Lp[-d], Lp[-d + 1]); acc0 += m.x * a0b.y; acc1 += m.y * a1b.y;
            m = *(const float2*)(Lp);            acc0 += m.x * a0b.z; acc1 += m.y * a1b.z;
            m = make_float2(Lp[d], Lp[d + 1]);   acc0 += m.x * a0b.w; acc1 += m.y * a1b.w;
        } else {
            m = *(const float2*)(Lm - d); acc0 += m.x * a0a.x; acc1 += m.y * a1a.x;
            m = *(const float2*)(Lm);     acc0 += m.x * a0a.y; acc1 += m.y * a1a.y;
            m = *(const float2*)(Lm + d); acc0 += m.x * a0a.z; acc1 += m.y * a1a.z;
            m = *(const float2*)(Lc - d); acc0 += m.x * a0a.w; acc1 += m.y * a1a.w;
            m = *(const float2*)(Lc + d); acc0 += m.x * a0b.x; acc1 += m.y * a1b.x;
            m = *(const float2*)(Lp - d); acc0 += m.x * a0b.y; acc1 += m.y * a1b.y;
            m = *(const float2*)(Lp);     acc0 += m.x * a0b.z; acc1 += m.y * a1b.z;
            m = *(const float2*)(Lp + d); acc0 += m.x * a0b.w; acc1 += m.y * a1b.w;
        }
    }
    *(float2*)(mout + (size_t)c * HW + t) = make_float2(acc0, acc1);
}

extern "C" void kernel_launch(void* const* d_in, const int* in_sizes, int n_in,
                              void* d_out, int out_size, void* d_ws, size_t ws_size,
                              hipStream_t stream) {
    const float* imgs  = (const float*)d_in[0];
    const float* masks = (const float*)d_in[1];
    float* out = (float*)d_out;

    float* ws = (float*)d_ws;
    float* imgs2 = ws;                       // CI*HW2 = 13467 -> pad to 16384
    float* aff2  = imgs2 + 16384;            // HW2*K  = 215472 (layout [HW2][K])
    float* afft  = aff2 + K * HW2;           // HW*K   = 2408448 (layout [HW][K])
    float* mA    = afft + (size_t)K * HW;    // CM*HW  = 1053696
    float* mB    = mA + (size_t)CM * HW;     // CM*HW  = 1053696

    // host-side positional softmax (input-independent, same every call)
    PosArr pos;
    {
        double pv[K];
        const int dil[ND] = {1, 2, 4, 8, 12, 24};
        const double s2 = sqrt(2.0);
        for (int di = 0; di < ND; ++di)
            for (int o = 0; o < 8; ++o) {
                double base = (o == 0 || o == 2 || o == 5 || o == 7) ? s2 : 1.0;
                pv[di * 8 + o] = base * (double)dil[di];
            }
        double sum = 0.0; for (int k = 0; k < K; ++k) sum += pv[k];
        double mean = sum / K;
        double ssd = 0.0; for (int k = 0; k < K; ++k) { double d0 = pv[k] - mean; ssd += d0 * d0; }
        double stdv = sqrt(ssd / (K - 1));
        double pa[K];
        double mx = -1e300;
        for (int k = 0; k < K; ++k) {
            double u = pv[k] / (stdv + 1e-8) / 0.3;
            pa[k] = -u * u;
            if (pa[k] > mx) mx = pa[k];
        }
        double es = 0.0, ev[K];
        for (int k = 0; k < K; ++k) { ev[k] = exp(pa[k] - mx); es += ev[k]; }
        for (int k = 0; k < K; ++k) pos.v[k] = (float)(ev[k] / es);
    }

    dim3 blk(256);
    k_img_down<<<(CI * HW2 + 255) / 256, blk, 0, stream>>>(imgs, imgs2);
    k_aff2<<<(HW2 * 64 + 255) / 256, blk, 0, stream>>>(imgs2, aff2);
    k_aff_total<<<(HW * 16 + 255) / 256, blk, 0, stream>>>(imgs, aff2, afft, pos);
    k_mask_up<<<(CM * HW + 255) / 256, blk, 0, stream>>>(masks, mA);

    float* bufs[2] = {mA, mB};
    const float* cur = mA;
    for (int i = 0; i < 10; ++i) {
        float* o = (i == 9) ? out : bufs[(i + 1) & 1];
        k_prop<<<1344, dim3(448), 0, stream>>>(cur, afft, o);
        cur = o;
    }
}

// Round 6
// 246.571 us; speedup vs baseline: 2.0264x; 2.0264x over previous
//
#include <hip/hip_runtime.h>
#include <math.h>

namespace {
constexpr int IH = 224, IW = 224;
constexpr int H2 = 67, W2 = 67;
constexpr int MH = 56, MW = 56;
constexpr int CI = 3, CM = 21;
constexpr int ND = 6;
constexpr int K = 48;
constexpr int HW = IH * IW;    // 50176
constexpr int HW2 = H2 * W2;   // 4489
constexpr float EPS = 1e-8f;
__device__ __constant__ int DILS_C[ND] = {1, 2, 4, 8, 12, 24};
}

struct PosArr { float v[K]; };

__device__ __forceinline__ float wsum64(float v) {
    #pragma unroll
    for (int off = 1; off < 64; off <<= 1) v += __shfl_xor(v, off);
    return v;
}

// ---------------- bilinear downsample imgs 224->67 (align_corners) ----------
__global__ void k_img_down(const float* __restrict__ img, float* __restrict__ img2) {
    int t = blockIdx.x * blockDim.x + threadIdx.x;
    if (t >= CI * HW2) return;
    int c = t / HW2, r = t % HW2;
    int y = r / W2, x = r % W2;
    float fy = (float)y * ((float)(IH - 1) / (float)(H2 - 1));
    float fx = (float)x * ((float)(IW - 1) / (float)(W2 - 1));
    int y0 = (int)floorf(fy); int y1 = min(y0 + 1, IH - 1); float wy = fy - (float)y0;
    int x0 = (int)floorf(fx); int x1 = min(x0 + 1, IW - 1); float wx = fx - (float)x0;
    const float* p = img + c * HW;
    float v00 = p[y0 * IW + x0], v01 = p[y0 * IW + x1];
    float v10 = p[y1 * IW + x0], v11 = p[y1 * IW + x1];
    float r0 = v00 * (1.f - wy) + v10 * wy;
    float r1 = v01 * (1.f - wy) + v11 * wy;
    img2[t] = r0 * (1.f - wx) + r1 * wx;
}

// ---------------- low-res affinity: one WAVE per pixel ----------------------
// aff2 layout [HW2][K]; stores sum over channels of (|n-center|/std)^2
__global__ void k_aff2(const float* __restrict__ img2, float* __restrict__ aff2) {
    int gtid = blockIdx.x * blockDim.x + threadIdx.x;
    int wave = gtid >> 6;
    int lane = threadIdx.x & 63;
    if (wave >= HW2) return;
    int t = wave;
    int y = t / W2, x = t % W2;

    int k = (lane < K) ? lane : (K - 1);
    int di = k >> 3, o = k & 7;
    int d = DILS_C[di];
    int ym = max(y - d, 0), yp = min(y + d, H2 - 1);
    int xm = max(x - d, 0), xp = min(x + d, W2 - 1);
    int ki = (0x22211000u >> (o * 4)) & 3;
    int kj = (0x21020210u >> (o * 4)) & 3;
    int ry = ki == 0 ? ym : (ki == 1 ? y : yp);
    int rx = kj == 0 ? xm : (kj == 1 ? x : xp);
    int nidx = ry * W2 + rx;

    float av = 0.f;
    #pragma unroll
    for (int c = 0; c < CI; ++c) {
        const float* p = img2 + c * HW2;
        float center = p[y * W2 + x];
        float v = p[nidx];
        float vv = (lane < K) ? v : 0.f;
        float s = wsum64(vv);
        float s2 = wsum64(vv * vv);
        float mean = s * (1.f / (float)K);
        float ss = s2 - (float)K * mean * mean;
        float stdv = sqrtf(fmaxf(ss, 0.f) * (1.f / (float)(K - 1)));
        float inv = 1.f / (stdv + EPS);
        float tt = fabsf(v - center) * inv;
        av += tt * tt;
    }
    if (lane < K) aff2[(size_t)t * K + k] = av;
}

// ---------------- full-res aff + upsampled aff2 + pos -> aff_total ----------
// 16 lanes per pixel (4 px/wave); lane handles k = lane, lane+16, lane+32.
// aff2 layout [HW2][K]; writes afft[t*K + k]
__global__ void k_aff_total(const float* __restrict__ img,
                            const float* __restrict__ aff2,
                            float* __restrict__ afft, PosArr pos) {
    int gid = blockIdx.x * blockDim.x + threadIdx.x;
    int t = gid >> 4;
    int lane = threadIdx.x & 15;
    if (t >= HW) return;
    int y = t / IW, x = t % IW;

    int nidx[3];
    int kk[3];
    #pragma unroll
    for (int s = 0; s < 3; ++s) {
        int k = lane + 16 * s;
        kk[s] = k;
        int di = k >> 3, o = k & 7;
        int d = DILS_C[di];
        int ki = (0x22211000u >> (o * 4)) & 3;
        int kj = (0x21020210u >> (o * 4)) & 3;
        int ym = max(y - d, 0), yp = min(y + d, IH - 1);
        int xm = max(x - d, 0), xp = min(x + d, IW - 1);
        int ry = ki == 0 ? ym : (ki == 1 ? y : yp);
        int rx = kj == 0 ? xm : (kj == 1 ? x : xp);
        nidx[s] = ry * IW + rx;
    }

    // full-res affinity accumulated over channels
    float av0 = 0.f, av1 = 0.f, av2 = 0.f;
    #pragma unroll
    for (int c = 0; c < CI; ++c) {
        const float* p = img + c * HW;
        float center = p[y * IW + x];
        float n0 = p[nidx[0]], n1 = p[nidx[1]], n2 = p[nidx[2]];
        float s1 = n0 + n1 + n2;
        float s2 = n0 * n0 + n1 * n1 + n2 * n2;
        #pragma unroll
        for (int off = 1; off < 16; off <<= 1) {
            s1 += __shfl_xor(s1, off, 16);
            s2 += __shfl_xor(s2, off, 16);
        }
        float mean = s1 * (1.f / (float)K);
        float ss = s2 - (float)K * mean * mean;
        float inv = 1.f / (sqrtf(fmaxf(ss, 0.f) * (1.f / (float)(K - 1))) + EPS);
        float t0 = fabsf(n0 - center) * inv; av0 += t0 * t0;
        float t1 = fabsf(n1 - center) * inv; av1 += t1 * t1;
        float t2 = fabsf(n2 - center) * inv; av2 += t2 * t2;
    }
    const float sc = -(1.f / (float)CI) / (0.3f * 0.3f);
    av0 *= sc; av1 *= sc; av2 *= sc;
    float m1 = fmaxf(av0, fmaxf(av1, av2));
    #pragma unroll
    for (int off = 1; off < 16; off <<= 1) m1 = fmaxf(m1, __shfl_xor(m1, off, 16));
    float e0 = expf(av0 - m1), e1 = expf(av1 - m1), e2 = expf(av2 - m1);
    float es = e0 + e1 + e2;
    #pragma unroll
    for (int off = 1; off < 16; off <<= 1) es += __shfl_xor(es, off, 16);
    float r1 = 1.f / es;

    // bilinear sample of aff2 (67->224, align_corners), then softmax
    float fy = (float)y * ((float)(H2 - 1) / (float)(IH - 1));
    float fx = (float)x * ((float)(W2 - 1) / (float)(IW - 1));
    int y0 = (int)floorf(fy); int y1 = min(y0 + 1, H2 - 1); float wy = fy - (float)y0;
    int x0 = (int)floorf(fx); int x1 = min(x0 + 1, W2 - 1); float wx = fx - (float)x0;
    const float* q00 = aff2 + (size_t)(y0 * W2 + x0) * K;
    const float* q01 = aff2 + (size_t)(y0 * W2 + x1) * K;
    const float* q10 = aff2 + (size_t)(y1 * W2 + x0) * K;
    const float* q11 = aff2 + (size_t)(y1 * W2 + x1) * K;
    float w00 = (1.f - wy) * (1.f - wx), w01 = (1.f - wy) * wx;
    float w10 = wy * (1.f - wx), w11 = wy * wx;
    const float sc2 = -(1.f / (float)CI);
    float b0 = (q00[kk[0]] * w00 + q01[kk[0]] * w01 + q10[kk[0]] * w10 + q11[kk[0]] * w11) * sc2;
    float b1 = (q00[kk[1]] * w00 + q01[kk[1]] * w01 + q10[kk[1]] * w10 + q11[kk[1]] * w11) * sc2;
    float b2 = (q00[kk[2]] * w00 + q01[kk[2]] * w01 + q10[kk[2]] * w10 + q11[kk[2]] * w11) * sc2;
    float m2 = fmaxf(b0, fmaxf(b1, b2));
    #pragma unroll
    for (int off = 1; off < 16; off <<= 1) m2 = fmaxf(m2, __shfl_xor(m2, off, 16));
    float f0 = expf(b0 - m2), f1 = expf(b1 - m2), f2 = expf(b2 - m2);
    float fs = f0 + f1 + f2;
    #pragma unroll
    for (int off = 1; off < 16; off <<= 1) fs += __shfl_xor(fs, off, 16);
    float r2 = 1.f / fs;

    float* o = afft + (size_t)t * K;
    o[kk[0]] = e0 * r1 + f0 * r2 + pos.v[kk[0]];
    o[kk[1]] = e1 * r1 + f1 * r2 + pos.v[kk[1]];
    o[kk[2]] = e2 * r1 + f2 * r2 + pos.v[kk[2]];
}

// ---------------- mask upsample 56 -> 224 -----------------------------------
__global__ void k_mask_up(const float* __restrict__ m, float* __restrict__ mu) {
    int t = blockIdx.x * blockDim.x + threadIdx.x;
    if (t >= CM * HW) return;
    int c = t / HW, r = t % HW;
    int y = r / IW, x = r % IW;
    float fy = (float)y * ((float)(MH - 1) / (float)(IH - 1));
    float fx = (float)x * ((float)(MW - 1) / (float)(IW - 1));
    int y0 = (int)floorf(fy); int y1 = min(y0 + 1, MH - 1); float wy = fy - (float)y0;
    int x0 = (int)floorf(fx); int x1 = min(x0 + 1, MW - 1); float wx = fx - (float)x0;
    const float* p = m + c * MH * MW;
    float v00 = p[y0 * MW + x0], v01 = p[y0 * MW + x1];
    float v10 = p[y1 * MW + x0], v11 = p[y1 * MW + x1];
    float r0 = v00 * (1.f - wy) + v10 * wy;
    float r1 = v01 * (1.f - wy) + v11 * wy;
    mu[t] = r0 * (1.f - wx) + r1 * wx;
}

// ---------------- one propagation iteration ---------------------------------
// Block = (image row y, 3-channel group). Stage 3 ch x 13 dy-rows x FULL
// 224-px row in LDS (34.9 KB -> 4 blocks/CU, 16 waves/CU). Staging is 39
// rows x 56 float4, fully coalesced. Compute: 224 threads, each 3 outputs,
// 144 stride-1 ds_read_b32 (conflict-free) + 12 hoisted float4 afft loads.
// Grid 224*7 = 1568 blocks, XCD-swizzled (28 contiguous rows per XCD).
__global__ __launch_bounds__(256) void k_prop(const float* __restrict__ min_,
                                              const float* __restrict__ afft,
                                              float* __restrict__ mout) {
    __shared__ float L[3 * 13 * 224];   // 34944 B
    int tid = threadIdx.x;
    int bid = blockIdx.x;
    int sw = (bid & 7) * 196 + (bid >> 3);   // 1568 = 8 * 196
    int y = sw / 7;
    int cg = sw - y * 7;
    int c0 = cg * 3;

    const int ROW_DY[13] = {-24, -12, -8, -4, -2, -1, 0, 1, 2, 4, 8, 12, 24};

    // ---- stage: 39 (ch,dy) rows x 224 px as float4
    for (int i = tid; i < 39 * 56; i += 256) {
        int ccr = i / 56;            // 0..38  (cc*13 + r)
        int xq  = i - ccr * 56;      // 0..55
        int cc  = ccr / 13;
        int r   = ccr - cc * 13;
        int gy  = min(max(y + ROW_DY[r], 0), IH - 1);
        const float4* src = (const float4*)(min_ + (size_t)(c0 + cc) * HW + gy * IW);
        *(float4*)(L + ccr * 224 + xq * 4) = src[xq];
    }
    __syncthreads();

    int x = tid;
    if (x >= IW) return;
    int t = y * IW + x;

    // hoist 48 affinity weights (12 float4)
    float a[K];
    {
        const float4* af = (const float4*)(afft + (size_t)t * K);
        #pragma unroll
        for (int i = 0; i < 12; ++i) {
            float4 v = af[i];
            a[4 * i + 0] = v.x; a[4 * i + 1] = v.y;
            a[4 * i + 2] = v.z; a[4 * i + 3] = v.w;
        }
    }

    const int DILS[ND] = {1, 2, 4, 8, 12, 24};
    const int RMI[ND] = {5, 4, 3, 2, 1, 0};
    const int RPI[ND] = {7, 8, 9, 10, 11, 12};
    int cm[ND], cp[ND];
    #pragma unroll
    for (int di = 0; di < ND; ++di) {
        cm[di] = max(x - DILS[di], 0);
        cp[di] = min(x + DILS[di], IW - 1);
    }

    float acc0 = 0.f, acc1 = 0.f, acc2 = 0.f;
    #pragma unroll
    for (int cc = 0; cc < 3; ++cc) {
        const float* Lb = L + cc * (13 * 224);
        const float* Lc = Lb + 6 * 224;
        float acc = 0.f;
        #pragma unroll
        for (int di = 0; di < ND; ++di) {
            const float* Lm = Lb + RMI[di] * 224;
            const float* Lp = Lb + RPI[di] * 224;
            int kb = di * 8;
            acc += Lm[cm[di]] * a[kb + 0];
            acc += Lm[x]      * a[kb + 1];
            acc += Lm[cp[di]] * a[kb + 2];
            acc += Lc[cm[di]] * a[kb + 3];
            acc += Lc[cp[di]] * a[kb + 4];
            acc += Lp[cm[di]] * a[kb + 5];
            acc += Lp[x]      * a[kb + 6];
            acc += Lp[cp[di]] * a[kb + 7];
        }
        if (cc == 0) acc0 = acc; else if (cc == 1) acc1 = acc; else acc2 = acc;
    }
    mout[(size_t)(c0 + 0) * HW + t] = acc0;
    mout[(size_t)(c0 + 1) * HW + t] = acc1;
    mout[(size_t)(c0 + 2) * HW + t] = acc2;
}

extern "C" void kernel_launch(void* const* d_in, const int* in_sizes, int n_in,
                              void* d_out, int out_size, void* d_ws, size_t ws_size,
                              hipStream_t stream) {
    const float* imgs  = (const float*)d_in[0];
    const float* masks = (const float*)d_in[1];
    float* out = (float*)d_out;

    float* ws = (float*)d_ws;
    float* imgs2 = ws;                       // CI*HW2 = 13467 -> pad to 16384
    float* aff2  = imgs2 + 16384;            // HW2*K  = 215472 (layout [HW2][K])
    float* afft  = aff2 + K * HW2;           // HW*K   = 2408448 (layout [HW][K])
    float* mA    = afft + (size_t)K * HW;    // CM*HW  = 1053696
    float* mB    = mA + (size_t)CM * HW;     // CM*HW  = 1053696

    // host-side positional softmax (input-independent, same every call)
    PosArr pos;
    {
        double pv[K];
        const int dil[ND] = {1, 2, 4, 8, 12, 24};
        const double s2 = sqrt(2.0);
        for (int di = 0; di < ND; ++di)
            for (int o = 0; o < 8; ++o) {
                double base = (o == 0 || o == 2 || o == 5 || o == 7) ? s2 : 1.0;
                pv[di * 8 + o] = base * (double)dil[di];
            }
        double sum = 0.0; for (int k = 0; k < K; ++k) sum += pv[k];
        double mean = sum / K;
        double ssd = 0.0; for (int k = 0; k < K; ++k) { double d0 = pv[k] - mean; ssd += d0 * d0; }
        double stdv = sqrt(ssd / (K - 1));
        double pa[K];
        double mx = -1e300;
        for (int k = 0; k < K; ++k) {
            double u = pv[k] / (stdv + 1e-8) / 0.3;
            pa[k] = -u * u;
            if (pa[k] > mx) mx = pa[k];
        }
        double es = 0.0, ev[K];
        for (int k = 0; k < K; ++k) { ev[k] = exp(pa[k] - mx); es += ev[k]; }
        for (int k = 0; k < K; ++k) pos.v[k] = (float)(ev[k] / es);
    }

    dim3 blk(256);
    k_img_down<<<(CI * HW2 + 255) / 256, blk, 0, stream>>>(imgs, imgs2);
    k_aff2<<<(HW2 * 64 + 255) / 256, blk, 0, stream>>>(imgs2, aff2);
    k_aff_total<<<(HW * 16 + 255) / 256, blk, 0, stream>>>(imgs, aff2, afft, pos);
    k_mask_up<<<(CM * HW + 255) / 256, blk, 0, stream>>>(masks, mA);

    float* bufs[2] = {mA, mB};
    const float* cur = mA;
    for (int i = 0; i < 10; ++i) {
        float* o = (i == 9) ? out : bufs[(i + 1) & 1];
        k_prop<<<1568, dim3(256), 0, stream>>>(cur, afft, o);
        cur = o;
    }
}

// Round 7
// 205.425 us; speedup vs baseline: 2.4323x; 1.2003x over previous
//
#include <hip/hip_runtime.h>
#include <hip/hip_fp16.h>
#include <math.h>

namespace {
constexpr int IH = 224, IW = 224;
constexpr int H2 = 67, W2 = 67;
constexpr int MH = 56, MW = 56;
constexpr int CI = 3, CM = 21;
constexpr int ND = 6;
constexpr int K = 48;
constexpr int HW = IH * IW;    // 50176
constexpr int HW2 = H2 * W2;   // 4489
constexpr float EPS = 1e-8f;
__device__ __constant__ int DILS_C[ND] = {1, 2, 4, 8, 12, 24};
}

struct PosArr { float v[K]; };

__device__ __forceinline__ float wsum64(float v) {
    #pragma unroll
    for (int off = 1; off < 64; off <<= 1) v += __shfl_xor(v, off);
    return v;
}

// ---------------- bilinear downsample imgs 224->67 (align_corners) ----------
__global__ void k_img_down(const float* __restrict__ img, float* __restrict__ img2) {
    int t = blockIdx.x * blockDim.x + threadIdx.x;
    if (t >= CI * HW2) return;
    int c = t / HW2, r = t % HW2;
    int y = r / W2, x = r % W2;
    float fy = (float)y * ((float)(IH - 1) / (float)(H2 - 1));
    float fx = (float)x * ((float)(IW - 1) / (float)(W2 - 1));
    int y0 = (int)floorf(fy); int y1 = min(y0 + 1, IH - 1); float wy = fy - (float)y0;
    int x0 = (int)floorf(fx); int x1 = min(x0 + 1, IW - 1); float wx = fx - (float)x0;
    const float* p = img + c * HW;
    float v00 = p[y0 * IW + x0], v01 = p[y0 * IW + x1];
    float v10 = p[y1 * IW + x0], v11 = p[y1 * IW + x1];
    float r0 = v00 * (1.f - wy) + v10 * wy;
    float r1 = v01 * (1.f - wy) + v11 * wy;
    img2[t] = r0 * (1.f - wx) + r1 * wx;
}

// ---------------- low-res affinity: one WAVE per pixel ----------------------
// aff2 layout [HW2][K]; stores sum over channels of (|n-center|/std)^2
__global__ void k_aff2(const float* __restrict__ img2, float* __restrict__ aff2) {
    int gtid = blockIdx.x * blockDim.x + threadIdx.x;
    int wave = gtid >> 6;
    int lane = threadIdx.x & 63;
    if (wave >= HW2) return;
    int t = wave;
    int y = t / W2, x = t % W2;

    int k = (lane < K) ? lane : (K - 1);
    int di = k >> 3, o = k & 7;
    int d = DILS_C[di];
    int ym = max(y - d, 0), yp = min(y + d, H2 - 1);
    int xm = max(x - d, 0), xp = min(x + d, W2 - 1);
    int ki = (0x22211000u >> (o * 4)) & 3;
    int kj = (0x21020210u >> (o * 4)) & 3;
    int ry = ki == 0 ? ym : (ki == 1 ? y : yp);
    int rx = kj == 0 ? xm : (kj == 1 ? x : xp);
    int nidx = ry * W2 + rx;

    float av = 0.f;
    #pragma unroll
    for (int c = 0; c < CI; ++c) {
        const float* p = img2 + c * HW2;
        float center = p[y * W2 + x];
        float v = p[nidx];
        float vv = (lane < K) ? v : 0.f;
        float s = wsum64(vv);
        float s2 = wsum64(vv * vv);
        float mean = s * (1.f / (float)K);
        float ss = s2 - (float)K * mean * mean;
        float stdv = sqrtf(fmaxf(ss, 0.f) * (1.f / (float)(K - 1)));
        float inv = 1.f / (stdv + EPS);
        float tt = fabsf(v - center) * inv;
        av += tt * tt;
    }
    if (lane < K) aff2[(size_t)t * K + k] = av;
}

// ---------------- full-res aff + upsampled aff2 + pos -> aff_total ----------
// 16 lanes per pixel (4 px/wave); lane handles k = lane, lane+16, lane+32.
// aff2 layout [HW2][K]; writes afft[t*K + k] as FP16
__global__ void k_aff_total(const float* __restrict__ img,
                            const float* __restrict__ aff2,
                            __half* __restrict__ afft, PosArr pos) {
    int gid = blockIdx.x * blockDim.x + threadIdx.x;
    int t = gid >> 4;
    int lane = threadIdx.x & 15;
    if (t >= HW) return;
    int y = t / IW, x = t % IW;

    int nidx[3];
    int kk[3];
    #pragma unroll
    for (int s = 0; s < 3; ++s) {
        int k = lane + 16 * s;
        kk[s] = k;
        int di = k >> 3, o = k & 7;
        int d = DILS_C[di];
        int ki = (0x22211000u >> (o * 4)) & 3;
        int kj = (0x21020210u >> (o * 4)) & 3;
        int ym = max(y - d, 0), yp = min(y + d, IH - 1);
        int xm = max(x - d, 0), xp = min(x + d, IW - 1);
        int ry = ki == 0 ? ym : (ki == 1 ? y : yp);
        int rx = kj == 0 ? xm : (kj == 1 ? x : xp);
        nidx[s] = ry * IW + rx;
    }

    // full-res affinity accumulated over channels
    float av0 = 0.f, av1 = 0.f, av2 = 0.f;
    #pragma unroll
    for (int c = 0; c < CI; ++c) {
        const float* p = img + c * HW;
        float center = p[y * IW + x];
        float n0 = p[nidx[0]], n1 = p[nidx[1]], n2 = p[nidx[2]];
        float s1 = n0 + n1 + n2;
        float s2 = n0 * n0 + n1 * n1 + n2 * n2;
        #pragma unroll
        for (int off = 1; off < 16; off <<= 1) {
            s1 += __shfl_xor(s1, off, 16);
            s2 += __shfl_xor(s2, off, 16);
        }
        float mean = s1 * (1.f / (float)K);
        float ss = s2 - (float)K * mean * mean;
        float inv = 1.f / (sqrtf(fmaxf(ss, 0.f) * (1.f / (float)(K - 1))) + EPS);
        float t0 = fabsf(n0 - center) * inv; av0 += t0 * t0;
        float t1 = fabsf(n1 - center) * inv; av1 += t1 * t1;
        float t2 = fabsf(n2 - center) * inv; av2 += t2 * t2;
    }
    const float sc = -(1.f / (float)CI) / (0.3f * 0.3f);
    av0 *= sc; av1 *= sc; av2 *= sc;
    float m1 = fmaxf(av0, fmaxf(av1, av2));
    #pragma unroll
    for (int off = 1; off < 16; off <<= 1) m1 = fmaxf(m1, __shfl_xor(m1, off, 16));
    float e0 = expf(av0 - m1), e1 = expf(av1 - m1), e2 = expf(av2 - m1);
    float es = e0 + e1 + e2;
    #pragma unroll
    for (int off = 1; off < 16; off <<= 1) es += __shfl_xor(es, off, 16);
    float r1 = 1.f / es;

    // bilinear sample of aff2 (67->224, align_corners), then softmax
    float fy = (float)y * ((float)(H2 - 1) / (float)(IH - 1));
    float fx = (float)x * ((float)(W2 - 1) / (float)(IW - 1));
    int y0 = (int)floorf(fy); int y1 = min(y0 + 1, H2 - 1); float wy = fy - (float)y0;
    int x0 = (int)floorf(fx); int x1 = min(x0 + 1, W2 - 1); float wx = fx - (float)x0;
    const float* q00 = aff2 + (size_t)(y0 * W2 + x0) * K;
    const float* q01 = aff2 + (size_t)(y0 * W2 + x1) * K;
    const float* q10 = aff2 + (size_t)(y1 * W2 + x0) * K;
    const float* q11 = aff2 + (size_t)(y1 * W2 + x1) * K;
    float w00 = (1.f - wy) * (1.f - wx), w01 = (1.f - wy) * wx;
    float w10 = wy * (1.f - wx), w11 = wy * wx;
    const float sc2 = -(1.f / (float)CI);
    float b0 = (q00[kk[0]] * w00 + q01[kk[0]] * w01 + q10[kk[0]] * w10 + q11[kk[0]] * w11) * sc2;
    float b1 = (q00[kk[1]] * w00 + q01[kk[1]] * w01 + q10[kk[1]] * w10 + q11[kk[1]] * w11) * sc2;
    float b2 = (q00[kk[2]] * w00 + q01[kk[2]] * w01 + q10[kk[2]] * w10 + q11[kk[2]] * w11) * sc2;
    float m2 = fmaxf(b0, fmaxf(b1, b2));
    #pragma unroll
    for (int off = 1; off < 16; off <<= 1) m2 = fmaxf(m2, __shfl_xor(m2, off, 16));
    float f0 = expf(b0 - m2), f1 = expf(b1 - m2), f2 = expf(b2 - m2);
    float fs = f0 + f1 + f2;
    #pragma unroll
    for (int off = 1; off < 16; off <<= 1) fs += __shfl_xor(fs, off, 16);
    float r2 = 1.f / fs;

    __half* o = afft + (size_t)t * K;
    o[kk[0]] = __float2half(e0 * r1 + f0 * r2 + pos.v[kk[0]]);
    o[kk[1]] = __float2half(e1 * r1 + f1 * r2 + pos.v[kk[1]]);
    o[kk[2]] = __float2half(e2 * r1 + f2 * r2 + pos.v[kk[2]]);
}

// ---------------- mask upsample 56 -> 224 -----------------------------------
__global__ void k_mask_up(const float* __restrict__ m, float* __restrict__ mu) {
    int t = blockIdx.x * blockDim.x + threadIdx.x;
    if (t >= CM * HW) return;
    int c = t / HW, r = t % HW;
    int y = r / IW, x = r % IW;
    float fy = (float)y * ((float)(MH - 1) / (float)(IH - 1));
    float fx = (float)x * ((float)(MW - 1) / (float)(IW - 1));
    int y0 = (int)floorf(fy); int y1 = min(y0 + 1, MH - 1); float wy = fy - (float)y0;
    int x0 = (int)floorf(fx); int x1 = min(x0 + 1, MW - 1); float wx = fx - (float)x0;
    const float* p = m + c * MH * MW;
    float v00 = p[y0 * MW + x0], v01 = p[y0 * MW + x1];
    float v10 = p[y1 * MW + x0], v11 = p[y1 * MW + x1];
    float r0 = v00 * (1.f - wy) + v10 * wy;
    float r1 = v01 * (1.f - wy) + v11 * wy;
    mu[t] = r0 * (1.f - wx) + r1 * wx;
}

// ---------------- one propagation iteration ---------------------------------
// Block = (row y, single channel c). LDS = 13 dy-rows x 224 px = 11.6 KB ->
// ~8 blocks/CU, 32 waves/CU. Staging: 13x56 float4, ~3/thread. afft (fp16,
// 96 B/px) loaded as 6 uint4 BEFORE the staging barrier (latency hidden).
// Grid 224*21 = 4704 blocks, XCD-swizzled: 28 contiguous rows per XCD.
__global__ __launch_bounds__(256) void k_prop(const float* __restrict__ min_,
                                              const __half* __restrict__ afft,
                                              float* __restrict__ mout) {
    __shared__ float L[13 * 224];   // 11648 B
    int tid = threadIdx.x;
    int bid = blockIdx.x;
    int sw = (bid & 7) * 588 + (bid >> 3);   // 4704 = 8 * 588, bijective
    int y = sw / 21;
    int c = sw - y * 21;

    // hoist affinity-weight loads (independent of LDS staging)
    int x = min(tid, IW - 1);
    int t = y * IW + x;
    uint4 w[6];
    {
        const uint4* aw = (const uint4*)(afft + (size_t)t * K);  // 96 B, 16B-aligned
        #pragma unroll
        for (int i = 0; i < 6; ++i) w[i] = aw[i];
    }

    // stage 13 rows x 224 px of channel c (full rows, coalesced float4)
    const int ROW_DY[13] = {-24, -12, -8, -4, -2, -1, 0, 1, 2, 4, 8, 12, 24};
    const float* mc = min_ + (size_t)c * HW;
    for (int i = tid; i < 13 * 56; i += 256) {
        int r = i / 56;
        int xq = i - r * 56;
        int gy = min(max(y + ROW_DY[r], 0), IH - 1);
        *(float4*)(L + r * 224 + xq * 4) = ((const float4*)(mc + gy * IW))[xq];
    }
    __syncthreads();

    if (tid >= IW) return;

    const int DILS[ND] = {1, 2, 4, 8, 12, 24};
    const int RMI[ND] = {5, 4, 3, 2, 1, 0};
    const int RPI[ND] = {7, 8, 9, 10, 11, 12};
    const float* Lc = L + 6 * 224;

    float acc = 0.f;
    #pragma unroll
    for (int di = 0; di < ND; ++di) {
        int d = DILS[di];
        int cm = max(x - d, 0);
        int cp = min(x + d, IW - 1);
        const float* Lm = L + RMI[di] * 224;
        const float* Lp = L + RPI[di] * 224;
        const __half2* hp = (const __half2*)&w[di];
        float2 f01 = __half22float2(hp[0]);
        float2 f23 = __half22float2(hp[1]);
        float2 f45 = __half22float2(hp[2]);
        float2 f67 = __half22float2(hp[3]);
        acc += Lm[cm] * f01.x;
        acc += Lm[x]  * f01.y;
        acc += Lm[cp] * f23.x;
        acc += Lc[cm] * f23.y;
        acc += Lc[cp] * f45.x;
        acc += Lp[cm] * f45.y;
        acc += Lp[x]  * f67.x;
        acc += Lp[cp] * f67.y;
    }
    mout[(size_t)c * HW + t] = acc;
}

extern "C" void kernel_launch(void* const* d_in, const int* in_sizes, int n_in,
                              void* d_out, int out_size, void* d_ws, size_t ws_size,
                              hipStream_t stream) {
    const float* imgs  = (const float*)d_in[0];
    const float* masks = (const float*)d_in[1];
    float* out = (float*)d_out;

    float* ws = (float*)d_ws;
    float* imgs2 = ws;                       // CI*HW2 = 13467 -> pad to 16384
    float* aff2  = imgs2 + 16384;            // HW2*K  = 215472 (layout [HW2][K])
    __half* afft = (__half*)(aff2 + K * HW2);       // HW*K halfs = 4.8 MB
    float* mA    = aff2 + K * HW2 + (K * HW) / 2;   // CM*HW floats
    float* mB    = mA + (size_t)CM * HW;

    // host-side positional softmax (input-independent, same every call)
    PosArr pos;
    {
        double pv[K];
        const int dil[ND] = {1, 2, 4, 8, 12, 24};
        const double s2 = sqrt(2.0);
        for (int di = 0; di < ND; ++di)
            for (int o = 0; o < 8; ++o) {
                double base = (o == 0 || o == 2 || o == 5 || o == 7) ? s2 : 1.0;
                pv[di * 8 + o] = base * (double)dil[di];
            }
        double sum = 0.0; for (int k = 0; k < K; ++k) sum += pv[k];
        double mean = sum / K;
        double ssd = 0.0; for (int k = 0; k < K; ++k) { double d0 = pv[k] - mean; ssd += d0 * d0; }
        double stdv = sqrt(ssd / (K - 1));
        double pa[K];
        double mx = -1e300;
        for (int k = 0; k < K; ++k) {
            double u = pv[k] / (stdv + 1e-8) / 0.3;
            pa[k] = -u * u;
            if (pa[k] > mx) mx = pa[k];
        }
        double es = 0.0, ev[K];
        for (int k = 0; k < K; ++k) { ev[k] = exp(pa[k] - mx); es += ev[k]; }
        for (int k = 0; k < K; ++k) pos.v[k] = (float)(ev[k] / es);
    }

    dim3 blk(256);
    k_img_down<<<(CI * HW2 + 255) / 256, blk, 0, stream>>>(imgs, imgs2);
    k_aff2<<<(HW2 * 64 + 255) / 256, blk, 0, stream>>>(imgs2, aff2);
    k_aff_total<<<(HW * 16 + 255) / 256, blk, 0, stream>>>(imgs, aff2, afft, pos);
    k_mask_up<<<(CM * HW + 255) / 256, blk, 0, stream>>>(masks, mA);

    float* bufs[2] = {mA, mB};
    const float* cur = mA;
    for (int i = 0; i < 10; ++i) {
        float* o = (i == 9) ? out : bufs[(i + 1) & 1];
        k_prop<<<4704, dim3(256), 0, stream>>>(cur, afft, o);
        cur = o;
    }
}